// Round 13
// baseline (227.841 us; speedup 1.0000x reference)
//
#include <hip/hip_runtime.h>
#include <math.h>

namespace {

typedef __attribute__((ext_vector_type(8))) short short8;
typedef __attribute__((ext_vector_type(4))) float f32x4;
typedef __attribute__((ext_vector_type(2))) float f32x2;

constexpr int B  = 2;
constexpr int C  = 256;
constexpr int NH = 8;
constexpr int L  = 4;
constexpr int P  = 4;
constexpr int D  = 32;
constexpr int LV = 13294;
constexpr int LQ = 13294;
constexpr int M  = B * LQ;      // 26588 rows for all GEMMs

constexpr int SZ[4]    = {100, 50, 25, 13};
constexpr int START[4] = {0, 10000, 12500, 13125};

__device__ inline short bf16r(float f) {    // RTNE f32 -> bf16
  unsigned u = __float_as_uint(f);
  u += 0x7fff + ((u >> 16) & 1);
  return (short)(u >> 16);
}

// 8 x f32 -> short8 bf16 via v_cvt_pk_bf16_f32 (RTNE, 1 instr / 2 elems).
__device__ inline short8 cvt8(const f32x4 lo, const f32x4 hi) {
  union { uint4 u; short8 s; } r;
  asm("v_cvt_pk_bf16_f32 %0, %1, %2" : "=v"(r.u.x) : "v"(lo[0]), "v"(lo[1]));
  asm("v_cvt_pk_bf16_f32 %0, %1, %2" : "=v"(r.u.y) : "v"(lo[2]), "v"(lo[3]));
  asm("v_cvt_pk_bf16_f32 %0, %1, %2" : "=v"(r.u.z) : "v"(hi[0]), "v"(hi[1]));
  asm("v_cvt_pk_bf16_f32 %0, %1, %2" : "=v"(r.u.w) : "v"(hi[2]), "v"(hi[3]));
  return r.s;
}

// A-fragment load straight from the f32 (len,B,C) tensor, converting
// in-register (no staging round-trip).
__device__ inline void load_a_cvt(const float* __restrict__ arow, short8 a[8]) {
#pragma unroll
  for (int s = 0; s < 8; ++s) {
    const f32x4 lo = *reinterpret_cast<const f32x4*>(arow + s * 32);
    const f32x4 hi = *reinterpret_cast<const f32x4*>(arow + s * 32 + 4);
    a[s] = cvt8(lo, hi);
  }
}

__device__ inline void load_a_bf16(const unsigned short* __restrict__ arow, short8 a[8]) {
#pragma unroll
  for (int s = 0; s < 8; ++s)
    a[s] = *reinterpret_cast<const short8*>(arow + s * 32);
}

// ---------------------------------------------------------------------------
// k_pre: weight transpose/convert (W[k][n] -> Bt[n][k] bf16), stored with
// each 512 B row XOR-SWIZZLED: 16B-slot k_phys = slot ^ (n&7). The GEMMs
// read b-fragments DIRECTLY from these rows in L2 (pattern proven correct
// by R12's fused epilogue); the XOR keeps quad-reads within 128B groups.
// ---------------------------------------------------------------------------
__global__ __launch_bounds__(256) void k_pre(
    const float* __restrict__ Wv, const float* __restrict__ Woff,
    const float* __restrict__ Wattn, const float* __restrict__ Wo,
    unsigned short* __restrict__ Btv, unsigned short* __restrict__ Btoa,
    unsigned short* __restrict__ Bto) {
  __shared__ float tile[32][33];
  const int blk = blockIdx.x;
  const float* src; unsigned short* dst; int N, local;
  if (blk < 64)       { src = Wv;    dst = Btv;              N = 256; local = blk; }
  else if (blk < 128) { src = Woff;  dst = Btoa;             N = 256; local = blk - 64; }
  else if (blk < 160) { src = Wattn; dst = Btoa + 256 * 256; N = 128; local = blk - 128; }
  else                { src = Wo;    dst = Bto;              N = 256; local = blk - 160; }
  const int ntiles = N >> 5;
  const int kt = local / ntiles, nt = local - kt * ntiles;
  const int k0 = kt << 5, n0 = nt << 5;
  const int tx = threadIdx.x & 31, ty = threadIdx.x >> 5;
#pragma unroll
  for (int r = 0; r < 4; ++r) {
    const int kk = ty + r * 8;
    tile[kk][tx] = src[(size_t)(k0 + kk) * N + n0 + tx];
  }
  __syncthreads();
#pragma unroll
  for (int r = 0; r < 4; ++r) {
    const int nn = ty + r * 8;
    const int n = n0 + nn, k = k0 + tx;
    dst[(size_t)n * 256 + (k ^ ((n & 7) << 3))] = (unsigned short)bf16r(tile[tx][nn]);
  }
}

// ---------------------------------------------------------------------------
// GEMM 1+2 (R13): BARRIER-FREE, ZERO-LDS — each wave streams its b-fragments
// directly from the swizzled Bt in L2 (917 KB total, resident across 832
// blocks) and owns 16 output rows x all N cols. Removes the serial
// barrier->stage->barrier skeleton entirely; loads of tile i+1 pipeline
// under MFMAs of tile i; no LDS occupancy cap.
//   blockIdx.y == 0: value x Wv        (16 col-tiles) -> val (bf16)
//   blockIdx.y == 1: query x Woff/attn (24 col-tiles) -> loc, attn
// ---------------------------------------------------------------------------
__global__ __launch_bounds__(256, 4) void k_gemm12(
    const float* __restrict__ query, const float* __restrict__ value,
    const float* __restrict__ rp,
    const unsigned short* __restrict__ Btv, const unsigned short* __restrict__ Btoa,
    const float* __restrict__ bv, const float* __restrict__ boff,
    const float* __restrict__ battn,
    unsigned short* __restrict__ val, float* __restrict__ loc,
    float* __restrict__ attn) {
  const int tid = threadIdx.x;
  const int wave = tid >> 6, lane = tid & 63, quad = lane >> 4, lo = lane & 15;
  const bool isval = (blockIdx.y == 0);
  const float* __restrict__ Af = isval ? value : query;
  const unsigned short* Bt  = isval ? Btv : Btoa;
  const int NT = isval ? 16 : 24;           // 16-col output tiles
  const int mrow = blockIdx.x * 64 + wave * 16;
  const int m = mrow + lo;                  // this lane's output row

  // A: load + convert once (full K=256 resident in registers).
  short8 a[8];
  {
    const int mr = min(m, M - 1);
    const int bb = mr / LQ, ii = mr - bb * LQ;    // source layout (len, B, C)
    load_a_cvt(Af + ((size_t)(ii * 2 + bb)) * 256 + quad * 8, a);
  }
  const int sw = lo & 7;                    // Bt-row XOR (row&7)

#pragma unroll 1
  for (int ttg = 0; ttg < NT; ++ttg) {
    // b-fragments straight from L2: row = ttg*16+lo, swizzled 16B slots.
    const unsigned short* bsrc = Bt + (size_t)(ttg * 16 + lo) * 256;
    short8 b[8];
#pragma unroll
    for (int s = 0; s < 8; ++s)
      b[s] = *reinterpret_cast<const short8*>(bsrc + (((quad + s * 4) ^ sw) << 3));
    f32x4 acc = (f32x4){0.f, 0.f, 0.f, 0.f};
#pragma unroll
    for (int s = 0; s < 8; ++s)
      acc = __builtin_amdgcn_mfma_f32_16x16x32_bf16(b[s], a[s], acc, 0, 0, 0);

    const int nb = ttg * 16 + quad * 4;     // this lane's 4 consecutive cols
    if (isval) {
      const f32x4 bias4 = *reinterpret_cast<const f32x4*>(bv + nb);
      const int h = nb >> 5, d0 = nb & 31;
      if (m < M) {
        const int bb = m / LV, i = m - bb * LV;
        ushort4 o;
        o.x = (unsigned short)bf16r(acc[0] + bias4[0]);
        o.y = (unsigned short)bf16r(acc[1] + bias4[1]);
        o.z = (unsigned short)bf16r(acc[2] + bias4[2]);
        o.w = (unsigned short)bf16r(acc[3] + bias4[3]);
        *reinterpret_cast<ushort4*>(
            val + (((size_t)(bb * NH + h)) * LV + i) * D + d0) = o;
      }
    } else if (ttg < 16) {                  // nb < 256: offsets -> loc
      const f32x4 bias4 = *reinterpret_cast<const f32x4*>(boff + nb);
      const int l = (nb >> 3) & 3;
      const float rsz = (l == 0) ? 0.01f : (l == 1) ? 0.02f
                      : (l == 2) ? 0.04f : (1.f / 13.f);
      if (m < M) {
        const float2 rv2 = *reinterpret_cast<const float2*>(rp + (size_t)m * 8 + l * 2);
        const float rx = fminf(fmaxf(rv2.x, 1e-5f), 1.f - 1e-5f);
        const float ry = fminf(fmaxf(rv2.y, 1e-5f), 1.f - 1e-5f);
        f32x4 o;
        o[0] = fmaf(acc[0] + bias4[0], rsz, rx);
        o[1] = fmaf(acc[1] + bias4[1], rsz, ry);
        o[2] = fmaf(acc[2] + bias4[2], rsz, rx);
        o[3] = fmaf(acc[3] + bias4[3], rsz, ry);
        *reinterpret_cast<f32x4*>(loc + (size_t)m * 256 + nb) = o;
      }
    } else {                                // attention logits -> softmax
      const int n2 = nb - 256;              // head*16 + 4-aligned col
      const f32x4 bias4 = *reinterpret_cast<const f32x4*>(battn + n2);
      float v0 = acc[0] + bias4[0], v1 = acc[1] + bias4[1];
      float v2 = acc[2] + bias4[2], v3 = acc[3] + bias4[3];
      float mx = fmaxf(fmaxf(v0, v1), fmaxf(v2, v3));
      mx = fmaxf(mx, __shfl_xor(mx, 16, 64));
      mx = fmaxf(mx, __shfl_xor(mx, 32, 64));
      const float e0 = __expf(v0 - mx), e1 = __expf(v1 - mx);
      const float e2 = __expf(v2 - mx), e3 = __expf(v3 - mx);
      float s = e0 + e1 + e2 + e3;
      s += __shfl_xor(s, 16, 64);
      s += __shfl_xor(s, 32, 64);
      const float inv = 1.f / s;
      if (m < M) {
        f32x4 o; o[0] = e0 * inv; o[1] = e1 * inv; o[2] = e2 * inv; o[3] = e3 * inv;
        *reinterpret_cast<f32x4*>(attn + (size_t)m * 128 + n2) = o;
      }
    }
  }
}

// ---------------------------------------------------------------------------
// GEMM 3 (R13: barrier-free, zero-LDS): out = tmp @ Wo + bo + query.
// ---------------------------------------------------------------------------
__global__ __launch_bounds__(256, 4) void k_gemm3(
    const unsigned short* __restrict__ tmp, const float* __restrict__ query,
    const unsigned short* __restrict__ Bt, const float* __restrict__ bo,
    float* __restrict__ out) {
  const int tid = threadIdx.x;
  const int wave = tid >> 6, lane = tid & 63, quad = lane >> 4, lo = lane & 15;
  const int mrow = blockIdx.x * 64 + wave * 16;
  const int m = mrow + lo;

  short8 a[8];
  {
    const int mr = min(m, M - 1);
    load_a_bf16(tmp + (size_t)mr * 256 + quad * 8, a);
  }
  const int sw = lo & 7;

#pragma unroll 1
  for (int ttg = 0; ttg < 16; ++ttg) {
    const unsigned short* bsrc = Bt + (size_t)(ttg * 16 + lo) * 256;
    short8 b[8];
#pragma unroll
    for (int s = 0; s < 8; ++s)
      b[s] = *reinterpret_cast<const short8*>(bsrc + (((quad + s * 4) ^ sw) << 3));
    f32x4 acc = (f32x4){0.f, 0.f, 0.f, 0.f};
#pragma unroll
    for (int s = 0; s < 8; ++s)
      acc = __builtin_amdgcn_mfma_f32_16x16x32_bf16(b[s], a[s], acc, 0, 0, 0);
    const int nb = ttg * 16 + quad * 4;
    const f32x4 bias4 = *reinterpret_cast<const f32x4*>(bo + nb);
    if (m < M) {
      const int bb = m / LQ, q = m - bb * LQ;
      const size_t o = ((size_t)(q * B + bb)) * C + nb;
      const f32x4 qv = *reinterpret_cast<const f32x4*>(query + o);
      f32x4 ov;
      ov[0] = acc[0] + bias4[0] + qv[0];
      ov[1] = acc[1] + bias4[1] + qv[1];
      ov[2] = acc[2] + bias4[2] + qv[2];
      ov[3] = acc[3] + bias4[3] + qv[3];
      *reinterpret_cast<f32x4*>(out + o) = ov;
    }
  }
}

// ---------------------------------------------------------------------------
// Bilinear sampling + attention weighting — EXACT R8/R11 version (55.4 us).
// ---------------------------------------------------------------------------
#define QB_I(v, PAT) __builtin_amdgcn_ds_swizzle((v), (PAT))
#define QB_F(v, PAT) __int_as_float(__builtin_amdgcn_ds_swizzle(__float_as_int(v), (PAT)))

__device__ inline void msda_corner(f32x2 acc[4], const uint4 r, const float w) {
  const f32x2 wv = {w, w};
  f32x2 v;
  v[0] = __uint_as_float(r.x << 16);
  v[1] = __uint_as_float(r.x & 0xffff0000u);
  acc[0] = __builtin_elementwise_fma(v, wv, acc[0]);
  v[0] = __uint_as_float(r.y << 16);
  v[1] = __uint_as_float(r.y & 0xffff0000u);
  acc[1] = __builtin_elementwise_fma(v, wv, acc[1]);
  v[0] = __uint_as_float(r.z << 16);
  v[1] = __uint_as_float(r.z & 0xffff0000u);
  acc[2] = __builtin_elementwise_fma(v, wv, acc[2]);
  v[0] = __uint_as_float(r.w << 16);
  v[1] = __uint_as_float(r.w & 0xffff0000u);
  acc[3] = __builtin_elementwise_fma(v, wv, acc[3]);
}

__global__ __launch_bounds__(256, 4) void k_sample(
    const unsigned short* __restrict__ val, const float* __restrict__ loc,
    const float* __restrict__ attn, unsigned short* __restrict__ tmp) {
  constexpr int QPB = 8;
  const int mblk = blockIdx.x * QPB;
  const int t = threadIdx.x;
  __shared__ float sloc[QPB * 8 * 33];    // [q][h][33]
  __shared__ float sattn[QPB * 8 * 17];   // [q][h][17]
  for (int i = t; i < QPB * 256; i += 256) {
    int mq = mblk + (i >> 8); if (mq >= M) mq = M - 1;
    const int j = i & 255;
    sloc[(((i >> 8) << 3) + (j >> 5)) * 33 + (j & 31)] = loc[(size_t)mq * 256 + j];
  }
  for (int i = t; i < QPB * 128; i += 256) {
    int mq = mblk + (i >> 7); if (mq >= M) mq = M - 1;
    const int j = i & 127;
    sattn[(((i >> 7) << 3) + (j >> 4)) * 17 + (j & 15)] = attn[(size_t)mq * 128 + j];
  }
  __syncthreads();

  const int g = t >> 5, s = t & 31, h = s >> 2, c8 = s & 3;
  const int m = mblk + g;
  const int mc = (m < M) ? m : M - 1;
  const int b = mc / LQ;
  const unsigned short* vhead = val + ((size_t)(b * NH + h) * LV) * D + c8 * 8;
  const float* ql = sloc + (g * 8 + h) * 33;
  const float* qa = sattn + (g * 8 + h) * 17;

  f32x2 acc[4];
  acc[0] = (f32x2){0.f, 0.f}; acc[1] = (f32x2){0.f, 0.f};
  acc[2] = (f32x2){0.f, 0.f}; acc[3] = (f32x2){0.f, 0.f};
#pragma unroll 1
  for (int l = 0; l < L; ++l) {
    const int Wl = SZ[l];
    const float Wlf = (float)Wl;
    const unsigned short* vlev = vhead + (size_t)START[l] * D;
    // Own point: p = c8. (Each quad lane computes one point's geometry.)
    const float x = ql[l * 8 + c8 * 2]     * Wlf - 0.5f;
    const float y = ql[l * 8 + c8 * 2 + 1] * Wlf - 0.5f;
    const float aw = qa[l * 4 + c8];
    const float x0f = floorf(x), y0f = floorf(y);
    const float wx = x - x0f, wy = y - y0f;
    const int x0 = (int)x0f, y0 = (int)y0f;
    const int x1 = x0 + 1, y1 = y0 + 1;
    const float wy1v = wy * aw;
    const float wy0m = ((unsigned)y0 < (unsigned)Wl) ? (aw - wy1v) : 0.f;
    const float wy1m = ((unsigned)y1 < (unsigned)Wl) ? wy1v : 0.f;
    const float wx0m = ((unsigned)x0 < (unsigned)Wl) ? (1.f - wx) : 0.f;
    const float wx1m = ((unsigned)x1 < (unsigned)Wl) ? wx : 0.f;
    const int xc0 = min(max(x0, 0), Wl - 1), xc1 = min(max(x1, 0), Wl - 1);
    const int yc0 = min(max(y0, 0), Wl - 1), yc1 = min(max(y1, 0), Wl - 1);
    const int r0 = yc0 * Wl, r1 = yc1 * Wl;
    const int o00 = (r0 + xc0) * D, o01 = (r0 + xc1) * D;
    const int o10 = (r1 + xc0) * D, o11 = (r1 + xc1) * D;
    const float w00 = wy0m * wx0m, w01 = wy0m * wx1m;
    const float w10 = wy1m * wx0m, w11 = wy1m * wx1m;

    // Phase 1: broadcast all 16 offsets + weights (quad-perm).
    int   off[16];
    float ww[16];
#define MSDA_BCAST(P, PAT)                                                \
    off[(P)*4+0] = QB_I(o00, PAT); off[(P)*4+1] = QB_I(o01, PAT);         \
    off[(P)*4+2] = QB_I(o10, PAT); off[(P)*4+3] = QB_I(o11, PAT);         \
    ww[(P)*4+0]  = QB_F(w00, PAT); ww[(P)*4+1]  = QB_F(w01, PAT);         \
    ww[(P)*4+2]  = QB_F(w10, PAT); ww[(P)*4+3]  = QB_F(w11, PAT);
    MSDA_BCAST(0, 0x8000)   // p=0: sel 0,0,0,0
    MSDA_BCAST(1, 0x8055)   // p=1: sel 1,1,1,1
    MSDA_BCAST(2, 0x80AA)   // p=2: sel 2,2,2,2
    MSDA_BCAST(3, 0x80FF)   // p=3: sel 3,3,3,3
#undef MSDA_BCAST

    // Phase 2: issue all 16 gathers (stay in flight together).
    uint4 v[16];
#pragma unroll
    for (int i = 0; i < 16; ++i)
      v[i] = *reinterpret_cast<const uint4*>(vlev + off[i]);

    // Phase 3: consume in identical point/corner order.
#pragma unroll
    for (int i = 0; i < 16; ++i)
      msda_corner(acc, v[i], ww[i]);
  }
  if (m < M) {
    short8 o;
#pragma unroll
    for (int j = 0; j < 4; ++j) {
      o[2 * j]     = bf16r(acc[j][0]);
      o[2 * j + 1] = bf16r(acc[j][1]);
    }
    *reinterpret_cast<short8*>(tmp + (size_t)m * 256 + h * 32 + c8 * 8) = o;
  }
}

}  // namespace

extern "C" void kernel_launch(void* const* d_in, const int* in_sizes, int n_in,
                              void* d_out, int out_size, void* d_ws, size_t ws_size,
                              hipStream_t stream) {
  const float* query = (const float*)d_in[0];
  const float* rp    = (const float*)d_in[1];
  const float* value = (const float*)d_in[2];
  const float* Wv    = (const float*)d_in[5];
  const float* bv    = (const float*)d_in[6];
  const float* Woff  = (const float*)d_in[7];
  const float* boff  = (const float*)d_in[8];
  const float* Wattn = (const float*)d_in[9];
  const float* battn = (const float*)d_in[10];
  const float* Wo    = (const float*)d_in[11];
  const float* bo    = (const float*)d_in[12];
  float* out = (float*)d_out;

  unsigned short* Btv  = (unsigned short*)d_ws;        // 256*256
  unsigned short* Btoa = Btv + 256 * 256;              // 384*256
  unsigned short* Bto  = Btoa + 384 * 256;             // 256*256
  unsigned short* val  = Bto + 256 * 256;              // M*256 bf16
  float* loc  = (float*)(val + (size_t)M * 256);       // M*256 f32
  float* attn = loc + (size_t)M * 256;                 // M*128 f32
  unsigned short* tmp = (unsigned short*)(attn + (size_t)M * 128);  // M*256 bf16

  const int mtiles64 = (M + 63) / 64;                  // 416
  const int sample_blocks = (M + 7) / 8;               // 3324

  k_pre<<<224, 256, 0, stream>>>(Wv, Woff, Wattn, Wo, Btv, Btoa, Bto);
  k_gemm12<<<dim3(mtiles64, 2), 256, 0, stream>>>(query, value, rp, Btv, Btoa,
                                                  bv, boff, battn, val, loc, attn);
  k_sample<<<sample_blocks, 256, 0, stream>>>(val, loc, attn, tmp);
  k_gemm3<<<mtiles64, 256, 0, stream>>>(tmp, query, Bto, bo, out);
}

// Round 14
// 203.763 us; speedup vs baseline: 1.1182x; 1.1182x over previous
//
#include <hip/hip_runtime.h>
#include <math.h>

namespace {

typedef __attribute__((ext_vector_type(8))) short short8;
typedef __attribute__((ext_vector_type(4))) float f32x4;
typedef __attribute__((ext_vector_type(2))) float f32x2;

constexpr int B  = 2;
constexpr int C  = 256;
constexpr int NH = 8;
constexpr int L  = 4;
constexpr int P  = 4;
constexpr int D  = 32;
constexpr int LV = 13294;
constexpr int LQ = 13294;
constexpr int M  = B * LQ;      // 26588 rows for all GEMMs

constexpr int SZ[4]    = {100, 50, 25, 13};
constexpr int START[4] = {0, 10000, 12500, 13125};

__device__ inline short bf16r(float f) {    // RTNE f32 -> bf16
  unsigned u = __float_as_uint(f);
  u += 0x7fff + ((u >> 16) & 1);
  return (short)(u >> 16);
}

// 8 x f32 -> short8 bf16 via v_cvt_pk_bf16_f32 (RTNE, 1 instr / 2 elems).
__device__ inline short8 cvt8(const f32x4 lo, const f32x4 hi) {
  union { uint4 u; short8 s; } r;
  asm("v_cvt_pk_bf16_f32 %0, %1, %2" : "=v"(r.u.x) : "v"(lo[0]), "v"(lo[1]));
  asm("v_cvt_pk_bf16_f32 %0, %1, %2" : "=v"(r.u.y) : "v"(lo[2]), "v"(lo[3]));
  asm("v_cvt_pk_bf16_f32 %0, %1, %2" : "=v"(r.u.z) : "v"(hi[0]), "v"(hi[1]));
  asm("v_cvt_pk_bf16_f32 %0, %1, %2" : "=v"(r.u.w) : "v"(hi[2]), "v"(hi[3]));
  return r.s;
}

// A-fragment load straight from the f32 (len,B,C) tensor, converting
// in-register (no staging round-trip).
__device__ inline void load_a_cvt(const float* __restrict__ arow, short8 a[8]) {
#pragma unroll
  for (int s = 0; s < 8; ++s) {
    const f32x4 lo = *reinterpret_cast<const f32x4*>(arow + s * 32);
    const f32x4 hi = *reinterpret_cast<const f32x4*>(arow + s * 32 + 4);
    a[s] = cvt8(lo, hi);
  }
}

__device__ inline void load_a_bf16(const unsigned short* __restrict__ arow, short8 a[8]) {
#pragma unroll
  for (int s = 0; s < 8; ++s)
    a[s] = *reinterpret_cast<const short8*>(arow + s * 32);
}

// Direct global->LDS DMA, 16 B/lane (wave-uniform LDS base + lane*16).
__device__ inline void glds16(const unsigned short* g, unsigned short* l) {
  __builtin_amdgcn_global_load_lds(
      (const __attribute__((address_space(1))) void*)g,
      (__attribute__((address_space(3))) void*)l, 16, 0, 0);
}

// ---------------------------------------------------------------------------
// k_pre: weight transpose/convert (W[k][n] -> Bt[n][k] bf16), stored with
// each 512 B row XOR-SWIZZLED: 16B-slot k_phys = slot ^ (n&7). GEMMs stage
// linearly via global_load_lds and XOR on the ds_read (R11 pattern).
// ---------------------------------------------------------------------------
__global__ __launch_bounds__(256) void k_pre(
    const float* __restrict__ Wv, const float* __restrict__ Woff,
    const float* __restrict__ Wattn, const float* __restrict__ Wo,
    unsigned short* __restrict__ Btv, unsigned short* __restrict__ Btoa,
    unsigned short* __restrict__ Bto) {
  __shared__ float tile[32][33];
  const int blk = blockIdx.x;
  const float* src; unsigned short* dst; int N, local;
  if (blk < 64)       { src = Wv;    dst = Btv;              N = 256; local = blk; }
  else if (blk < 128) { src = Woff;  dst = Btoa;             N = 256; local = blk - 64; }
  else if (blk < 160) { src = Wattn; dst = Btoa + 256 * 256; N = 128; local = blk - 128; }
  else                { src = Wo;    dst = Bto;              N = 256; local = blk - 160; }
  const int ntiles = N >> 5;
  const int kt = local / ntiles, nt = local - kt * ntiles;
  const int k0 = kt << 5, n0 = nt << 5;
  const int tx = threadIdx.x & 31, ty = threadIdx.x >> 5;
#pragma unroll
  for (int r = 0; r < 4; ++r) {
    const int kk = ty + r * 8;
    tile[kk][tx] = src[(size_t)(k0 + kk) * N + n0 + tx];
  }
  __syncthreads();
#pragma unroll
  for (int r = 0; r < 4; ++r) {
    const int nn = ty + r * 8;
    const int n = n0 + nn, k = k0 + tx;
    dst[(size_t)n * 256 + (k ^ ((n & 7) << 3))] = (unsigned short)bf16r(tile[tx][nn]);
  }
}

// ---------------------------------------------------------------------------
// GEMM 1+2 (R14): DOUBLE-BUFFERED glds staging — 32-row chunks (2x16 KB
// LDS, still 4 blocks/CU). Chunk ch+1's DMA is issued right after the
// barrier that publishes chunk ch, so the compiler's vmcnt(0)-before-
// barrier drain lands AFTER the compute phase: staging latency hides
// under MFMAs. One barrier per chunk (same count as R11, zero exposed
// staging latency). Math identical to R11 -> bit-identical output.
//   blockIdx.y == 0: value x Wv        (8 chunks)  -> val (bf16)
//   blockIdx.y == 1: query x Woff/attn (12 chunks) -> loc, attn
// ---------------------------------------------------------------------------
__global__ __launch_bounds__(256, 4) void k_gemm12(
    const float* __restrict__ query, const float* __restrict__ value,
    const float* __restrict__ rp,
    const unsigned short* __restrict__ Btv, const unsigned short* __restrict__ Btoa,
    const float* __restrict__ bv, const float* __restrict__ boff,
    const float* __restrict__ battn,
    unsigned short* __restrict__ val, float* __restrict__ loc,
    float* __restrict__ attn) {
  __shared__ unsigned short sB[2][32 * 256];  // 2 x 16 KB (swizzled content)
  __shared__ float sRP[64][9];                // 2.3 KB clamped rp cache (y=1)
  const int tid = threadIdx.x;
  const int wave = tid >> 6, lane = tid & 63, quad = lane >> 4, lo = lane & 15;
  const bool isval = (blockIdx.y == 0);
  const float* __restrict__ Af = isval ? value : query;
  const unsigned short* Bt  = isval ? Btv : Btoa;
  const int NC = isval ? 8 : 12;              // 32-col chunks
  const int m0 = blockIdx.x * 64;
  const int mrow = m0 + wave * 16;            // this wave's 16 output rows
  const int m = mrow + lo;

  // A: load + convert once (full K=256 resident in registers).
  short8 a[8];
  {
    const int mr = min(m, M - 1);
    const int bb = mr / LQ, ii = mr - bb * LQ;    // source layout (len, B, C)
    load_a_cvt(Af + ((size_t)(ii * 2 + bb)) * 256 + quad * 8, a);
  }

  if (!isval && tid < 128) {
    // Stage clamped rp rows for this M-tile: 64 rows x 8 floats, 2 thr/row.
    const int r = tid >> 1, q4 = (tid & 1) * 4;
    const int mr = min(m0 + r, M - 1);
    f32x4 v = *reinterpret_cast<const f32x4*>(rp + (size_t)mr * 8 + q4);
#pragma unroll
    for (int j = 0; j < 4; ++j) v[j] = fminf(fmaxf(v[j], 1e-5f), 1.f - 1e-5f);
    *reinterpret_cast<f32x4*>(&sRP[r][q4]) = v;
  }

  const int sw = lo & 7;                      // ds_read slot XOR (row&7)

  // STAGE(buf, ch): chunk = 32 rows x 512 B = 16 KB, 4 x 1KB DMA per wave.
#define STAGE14(BUF, CH)                                                    \
  {                                                                         \
    const unsigned short* gsrc = Bt + (size_t)(CH) * 8192 + wave * 2048 + lane * 8; \
    unsigned short* lbase = &sB[(BUF)][wave * 2048];                        \
    glds16(gsrc,        lbase);                                             \
    glds16(gsrc + 512,  lbase + 512);                                       \
    glds16(gsrc + 1024, lbase + 1024);                                      \
    glds16(gsrc + 1536, lbase + 1536);                                      \
  }

  STAGE14(0, 0)
  int cur = 0;
#pragma unroll 1
  for (int ch = 0; ch < NC; ++ch) {
    __syncthreads();                 // drains DMA: buf[cur] ready (also fences sRP)
    if (ch + 1 < NC) STAGE14(cur ^ 1, ch + 1)   // async: hides under compute

#pragma unroll
    for (int tt = 0; tt < 2; ++tt) {
      const unsigned short* bbase = &sB[cur][(tt * 16 + lo) * 256];
      short8 b[8];
#pragma unroll
      for (int s = 0; s < 8; ++s)
        b[s] = *reinterpret_cast<const short8*>(bbase + (((quad + s * 4) ^ sw) << 3));
      f32x4 acc = (f32x4){0.f, 0.f, 0.f, 0.f};
#pragma unroll
      for (int s = 0; s < 8; ++s)
        acc = __builtin_amdgcn_mfma_f32_16x16x32_bf16(b[s], a[s], acc, 0, 0, 0);

      const int nb = ch * 32 + tt * 16 + quad * 4;  // this lane's 4 cols
      if (isval) {
        const f32x4 bias4 = *reinterpret_cast<const f32x4*>(bv + nb);
        const int h = nb >> 5, d0 = nb & 31;
        if (m < M) {
          const int bb = m / LV, i = m - bb * LV;
          ushort4 o;
          o.x = (unsigned short)bf16r(acc[0] + bias4[0]);
          o.y = (unsigned short)bf16r(acc[1] + bias4[1]);
          o.z = (unsigned short)bf16r(acc[2] + bias4[2]);
          o.w = (unsigned short)bf16r(acc[3] + bias4[3]);
          *reinterpret_cast<ushort4*>(
              val + (((size_t)(bb * NH + h)) * LV + i) * D + d0) = o;
        }
      } else if (ch < 8) {                      // nb < 256: offsets -> loc
        const f32x4 bias4 = *reinterpret_cast<const f32x4*>(boff + nb);
        const int l = (nb >> 3) & 3;
        const float rsz = (l == 0) ? 0.01f : (l == 1) ? 0.02f
                        : (l == 2) ? 0.04f : (1.f / 13.f);
        if (m < M) {
          const int lr = wave * 16 + lo;        // row in sRP
          const float rx = sRP[lr][l * 2];
          const float ry = sRP[lr][l * 2 + 1];
          f32x4 o;
          o[0] = fmaf(acc[0] + bias4[0], rsz, rx);
          o[1] = fmaf(acc[1] + bias4[1], rsz, ry);
          o[2] = fmaf(acc[2] + bias4[2], rsz, rx);
          o[3] = fmaf(acc[3] + bias4[3], rsz, ry);
          *reinterpret_cast<f32x4*>(loc + (size_t)m * 256 + nb) = o;
        }
      } else {                                  // attention logits -> softmax
        const int n2 = nb - 256;                // head*16 + 4-aligned col
        const f32x4 bias4 = *reinterpret_cast<const f32x4*>(battn + n2);
        float v0 = acc[0] + bias4[0], v1 = acc[1] + bias4[1];
        float v2 = acc[2] + bias4[2], v3 = acc[3] + bias4[3];
        float mx = fmaxf(fmaxf(v0, v1), fmaxf(v2, v3));
        mx = fmaxf(mx, __shfl_xor(mx, 16, 64));
        mx = fmaxf(mx, __shfl_xor(mx, 32, 64));
        const float e0 = __expf(v0 - mx), e1 = __expf(v1 - mx);
        const float e2 = __expf(v2 - mx), e3 = __expf(v3 - mx);
        float s = e0 + e1 + e2 + e3;
        s += __shfl_xor(s, 16, 64);
        s += __shfl_xor(s, 32, 64);
        const float inv = 1.f / s;
        if (m < M) {
          f32x4 o; o[0] = e0 * inv; o[1] = e1 * inv; o[2] = e2 * inv; o[3] = e3 * inv;
          *reinterpret_cast<f32x4*>(attn + (size_t)m * 128 + n2) = o;
        }
      }
    }
    cur ^= 1;
  }
}

// ---------------------------------------------------------------------------
// GEMM 3 (R14: same double-buffered glds staging, 8 chunks):
// out = tmp @ Wo + bo + query.
// ---------------------------------------------------------------------------
__global__ __launch_bounds__(256, 4) void k_gemm3(
    const unsigned short* __restrict__ tmp, const float* __restrict__ query,
    const unsigned short* __restrict__ Bt, const float* __restrict__ bo,
    float* __restrict__ out) {
  __shared__ unsigned short sB[2][32 * 256];  // 2 x 16 KB
  const int tid = threadIdx.x;
  const int wave = tid >> 6, lane = tid & 63, quad = lane >> 4, lo = lane & 15;
  const int m0 = blockIdx.x * 64;
  const int mrow = m0 + wave * 16;
  const int m = mrow + lo;

  short8 a[8];
  {
    const int mr = min(m, M - 1);
    load_a_bf16(tmp + (size_t)mr * 256 + quad * 8, a);
  }
  const int sw = lo & 7;

  STAGE14(0, 0)
  int cur = 0;
#pragma unroll 1
  for (int ch = 0; ch < 8; ++ch) {
    __syncthreads();
    if (ch + 1 < 8) STAGE14(cur ^ 1, ch + 1)

#pragma unroll
    for (int tt = 0; tt < 2; ++tt) {
      const unsigned short* bbase = &sB[cur][(tt * 16 + lo) * 256];
      short8 b[8];
#pragma unroll
      for (int s = 0; s < 8; ++s)
        b[s] = *reinterpret_cast<const short8*>(bbase + (((quad + s * 4) ^ sw) << 3));
      f32x4 acc = (f32x4){0.f, 0.f, 0.f, 0.f};
#pragma unroll
      for (int s = 0; s < 8; ++s)
        acc = __builtin_amdgcn_mfma_f32_16x16x32_bf16(b[s], a[s], acc, 0, 0, 0);
      const int nb = ch * 32 + tt * 16 + quad * 4;
      const f32x4 bias4 = *reinterpret_cast<const f32x4*>(bo + nb);
      if (m < M) {
        const int bb = m / LQ, q = m - bb * LQ;
        const size_t o = ((size_t)(q * B + bb)) * C + nb;
        const f32x4 qv = *reinterpret_cast<const f32x4*>(query + o);
        f32x4 ov;
        ov[0] = acc[0] + bias4[0] + qv[0];
        ov[1] = acc[1] + bias4[1] + qv[1];
        ov[2] = acc[2] + bias4[2] + qv[2];
        ov[3] = acc[3] + bias4[3] + qv[3];
        *reinterpret_cast<f32x4*>(out + o) = ov;
      }
    }
    cur ^= 1;
  }
}
#undef STAGE14

// ---------------------------------------------------------------------------
// Bilinear sampling + attention weighting — EXACT R8/R11 version (55.4 us).
// ---------------------------------------------------------------------------
#define QB_I(v, PAT) __builtin_amdgcn_ds_swizzle((v), (PAT))
#define QB_F(v, PAT) __int_as_float(__builtin_amdgcn_ds_swizzle(__float_as_int(v), (PAT)))

__device__ inline void msda_corner(f32x2 acc[4], const uint4 r, const float w) {
  const f32x2 wv = {w, w};
  f32x2 v;
  v[0] = __uint_as_float(r.x << 16);
  v[1] = __uint_as_float(r.x & 0xffff0000u);
  acc[0] = __builtin_elementwise_fma(v, wv, acc[0]);
  v[0] = __uint_as_float(r.y << 16);
  v[1] = __uint_as_float(r.y & 0xffff0000u);
  acc[1] = __builtin_elementwise_fma(v, wv, acc[1]);
  v[0] = __uint_as_float(r.z << 16);
  v[1] = __uint_as_float(r.z & 0xffff0000u);
  acc[2] = __builtin_elementwise_fma(v, wv, acc[2]);
  v[0] = __uint_as_float(r.w << 16);
  v[1] = __uint_as_float(r.w & 0xffff0000u);
  acc[3] = __builtin_elementwise_fma(v, wv, acc[3]);
}

__global__ __launch_bounds__(256, 4) void k_sample(
    const unsigned short* __restrict__ val, const float* __restrict__ loc,
    const float* __restrict__ attn, unsigned short* __restrict__ tmp) {
  constexpr int QPB = 8;
  const int mblk = blockIdx.x * QPB;
  const int t = threadIdx.x;
  __shared__ float sloc[QPB * 8 * 33];    // [q][h][33]
  __shared__ float sattn[QPB * 8 * 17];   // [q][h][17]
  for (int i = t; i < QPB * 256; i += 256) {
    int mq = mblk + (i >> 8); if (mq >= M) mq = M - 1;
    const int j = i & 255;
    sloc[(((i >> 8) << 3) + (j >> 5)) * 33 + (j & 31)] = loc[(size_t)mq * 256 + j];
  }
  for (int i = t; i < QPB * 128; i += 256) {
    int mq = mblk + (i >> 7); if (mq >= M) mq = M - 1;
    const int j = i & 127;
    sattn[(((i >> 7) << 3) + (j >> 4)) * 17 + (j & 15)] = attn[(size_t)mq * 128 + j];
  }
  __syncthreads();

  const int g = t >> 5, s = t & 31, h = s >> 2, c8 = s & 3;
  const int m = mblk + g;
  const int mc = (m < M) ? m : M - 1;
  const int b = mc / LQ;
  const unsigned short* vhead = val + ((size_t)(b * NH + h) * LV) * D + c8 * 8;
  const float* ql = sloc + (g * 8 + h) * 33;
  const float* qa = sattn + (g * 8 + h) * 17;

  f32x2 acc[4];
  acc[0] = (f32x2){0.f, 0.f}; acc[1] = (f32x2){0.f, 0.f};
  acc[2] = (f32x2){0.f, 0.f}; acc[3] = (f32x2){0.f, 0.f};
#pragma unroll 1
  for (int l = 0; l < L; ++l) {
    const int Wl = SZ[l];
    const float Wlf = (float)Wl;
    const unsigned short* vlev = vhead + (size_t)START[l] * D;
    // Own point: p = c8. (Each quad lane computes one point's geometry.)
    const float x = ql[l * 8 + c8 * 2]     * Wlf - 0.5f;
    const float y = ql[l * 8 + c8 * 2 + 1] * Wlf - 0.5f;
    const float aw = qa[l * 4 + c8];
    const float x0f = floorf(x), y0f = floorf(y);
    const float wx = x - x0f, wy = y - y0f;
    const int x0 = (int)x0f, y0 = (int)y0f;
    const int x1 = x0 + 1, y1 = y0 + 1;
    const float wy1v = wy * aw;
    const float wy0m = ((unsigned)y0 < (unsigned)Wl) ? (aw - wy1v) : 0.f;
    const float wy1m = ((unsigned)y1 < (unsigned)Wl) ? wy1v : 0.f;
    const float wx0m = ((unsigned)x0 < (unsigned)Wl) ? (1.f - wx) : 0.f;
    const float wx1m = ((unsigned)x1 < (unsigned)Wl) ? wx : 0.f;
    const int xc0 = min(max(x0, 0), Wl - 1), xc1 = min(max(x1, 0), Wl - 1);
    const int yc0 = min(max(y0, 0), Wl - 1), yc1 = min(max(y1, 0), Wl - 1);
    const int r0 = yc0 * Wl, r1 = yc1 * Wl;
    const int o00 = (r0 + xc0) * D, o01 = (r0 + xc1) * D;
    const int o10 = (r1 + xc0) * D, o11 = (r1 + xc1) * D;
    const float w00 = wy0m * wx0m, w01 = wy0m * wx1m;
    const float w10 = wy1m * wx0m, w11 = wy1m * wx1m;

    // Phase 1: broadcast all 16 offsets + weights (quad-perm).
    int   off[16];
    float ww[16];
#define MSDA_BCAST(P, PAT)                                                \
    off[(P)*4+0] = QB_I(o00, PAT); off[(P)*4+1] = QB_I(o01, PAT);         \
    off[(P)*4+2] = QB_I(o10, PAT); off[(P)*4+3] = QB_I(o11, PAT);         \
    ww[(P)*4+0]  = QB_F(w00, PAT); ww[(P)*4+1]  = QB_F(w01, PAT);         \
    ww[(P)*4+2]  = QB_F(w10, PAT); ww[(P)*4+3]  = QB_F(w11, PAT);
    MSDA_BCAST(0, 0x8000)   // p=0: sel 0,0,0,0
    MSDA_BCAST(1, 0x8055)   // p=1: sel 1,1,1,1
    MSDA_BCAST(2, 0x80AA)   // p=2: sel 2,2,2,2
    MSDA_BCAST(3, 0x80FF)   // p=3: sel 3,3,3,3
#undef MSDA_BCAST

    // Phase 2: issue all 16 gathers (stay in flight together).
    uint4 v[16];
#pragma unroll
    for (int i = 0; i < 16; ++i)
      v[i] = *reinterpret_cast<const uint4*>(vlev + off[i]);

    // Phase 3: consume in identical point/corner order.
#pragma unroll
    for (int i = 0; i < 16; ++i)
      msda_corner(acc, v[i], ww[i]);
  }
  if (m < M) {
    short8 o;
#pragma unroll
    for (int j = 0; j < 4; ++j) {
      o[2 * j]     = bf16r(acc[j][0]);
      o[2 * j + 1] = bf16r(acc[j][1]);
    }
    *reinterpret_cast<short8*>(tmp + (size_t)m * 256 + h * 32 + c8 * 8) = o;
  }
}

}  // namespace

extern "C" void kernel_launch(void* const* d_in, const int* in_sizes, int n_in,
                              void* d_out, int out_size, void* d_ws, size_t ws_size,
                              hipStream_t stream) {
  const float* query = (const float*)d_in[0];
  const float* rp    = (const float*)d_in[1];
  const float* value = (const float*)d_in[2];
  const float* Wv    = (const float*)d_in[5];
  const float* bv    = (const float*)d_in[6];
  const float* Woff  = (const float*)d_in[7];
  const float* boff  = (const float*)d_in[8];
  const float* Wattn = (const float*)d_in[9];
  const float* battn = (const float*)d_in[10];
  const float* Wo    = (const float*)d_in[11];
  const float* bo    = (const float*)d_in[12];
  float* out = (float*)d_out;

  unsigned short* Btv  = (unsigned short*)d_ws;        // 256*256
  unsigned short* Btoa = Btv + 256 * 256;              // 384*256
  unsigned short* Bto  = Btoa + 384 * 256;             // 256*256
  unsigned short* val  = Bto + 256 * 256;              // M*256 bf16
  float* loc  = (float*)(val + (size_t)M * 256);       // M*256 f32
  float* attn = loc + (size_t)M * 256;                 // M*128 f32
  unsigned short* tmp = (unsigned short*)(attn + (size_t)M * 128);  // M*256 bf16

  const int mtiles64 = (M + 63) / 64;                  // 416
  const int sample_blocks = (M + 7) / 8;               // 3324

  k_pre<<<224, 256, 0, stream>>>(Wv, Woff, Wattn, Wo, Btv, Btoa, Bto);
  k_gemm12<<<dim3(mtiles64, 2), 256, 0, stream>>>(query, value, rp, Btv, Btoa,
                                                  bv, boff, battn, val, loc, attn);
  k_sample<<<sample_blocks, 256, 0, stream>>>(val, loc, attn, tmp);
  k_gemm3<<<mtiles64, 256, 0, stream>>>(tmp, query, Bto, bo, out);
}